// Round 5
// baseline (171.668 us; speedup 1.0000x reference)
//
#include <hip/hip_runtime.h>

#define NA 1000
#define NCH 4
#define CHUNK 250              // NA / NCH
#define ND 513
#define IMG 512
#define CROP 362
#define TOP ((IMG - CROP) / 2) // 75
#define NPIX (CROP * CROP)     // 131044
#define NTILE 23               // ceil(362/16)

typedef __fp16 half2_t __attribute__((ext_vector_type(2)));

// Static device buffers, fully rewritten every call (deterministic).
// g_pk: [angle][det][8 f16 batches] -> 16 B cells; cells i0,i0+1 contiguous.
// g_part: [chunk][batch][pix] f32 partial sums.
__device__ float2 g_tab[NA];
__device__ uint4  g_pk[(size_t)NA * ND];
__device__ float  g_part[(size_t)NCH * 8 * NPIX];

__global__ void table_kernel() {
    int a = blockIdx.x * blockDim.x + threadIdx.x;
    if (a >= NA) return;
    double th = (double)a * (3.14159265358979323846 / (double)NA);
    float delta_f = (float)(2.0 * 0.13 / (double)(ND - 1));
    double inv = 1.0 / (double)delta_f;
    g_tab[a] = make_float2((float)(cos(th) * inv), (float)(sin(th) * inv));
}

// x[b][a][d] (b-major, f32) -> g_pk[a*ND+d] = 8 f16 (batches 0..7), RNE.
__global__ void pack_kernel(const float* __restrict__ x) {
    int t = blockIdx.x * blockDim.x + threadIdx.x;   // t = a*ND + d
    if (t >= NA * ND) return;
    const int S = NA * ND;
    unsigned int w[4];
    #pragma unroll
    for (int b = 0; b < 4; ++b) {
        half2_t h;
        h.x = (__fp16)x[(size_t)(2 * b) * S + t];
        h.y = (__fp16)x[(size_t)(2 * b + 1) * S + t];
        __builtin_memcpy(&w[b], &h, 4);
    }
    uint4 o;
    o.x = w[0]; o.y = w[1]; o.z = w[2]; o.w = w[3];
    g_pk[t] = o;
}

__device__ __forceinline__ float dot2(unsigned int pair, half2_t wp, float acc) {
    half2_t h; __builtin_memcpy(&h, &pair, 4);
    float d;
    asm("v_dot2_f32_f16 %0, %1, %2, %3" : "=v"(d) : "v"(h), "v"(wp), "v"(acc));
    return d;
}

// block = 256 thr; each wave owns an 8x8 pixel patch (gather span ~11 cells).
// grid = (tileJ=23, tileI=23, chunk=4). One thread: 1 pixel x 8 batches x 250 angles.
__launch_bounds__(256)
__global__ void bp_kernel() {
    __shared__ float2 s_tab[CHUNK];
    int ch = blockIdx.z;
    int a0 = ch * CHUNK;
    for (int t = threadIdx.x; t < CHUNK; t += 256) s_tab[t] = g_tab[a0 + t];
    __syncthreads();

    int wave = threadIdx.x >> 6;
    int lane = threadIdx.x & 63;
    int ti = (wave >> 1) * 8 + (lane >> 3);
    int tj = (wave & 1) * 8 + (lane & 7);
    int i = blockIdx.y * 16 + ti;      // -> X
    int j = blockIdx.x * 16 + tj;      // -> Y
    int ic = min(i, CROP - 1);
    int jc = min(j, CROP - 1);

    const float step = (float)(0.26 / 511.0);
    float X = fmaf((float)(TOP + ic), step, -0.13f);
    float Y = fmaf((float)(TOP + jc), step, -0.13f);

    const uint4* __restrict__ cell = g_pk + (size_t)a0 * ND;

    float acc0 = 0.f, acc1 = 0.f, acc2 = 0.f, acc3 = 0.f;
    float acc4 = 0.f, acc5 = 0.f, acc6 = 0.f, acc7 = 0.f;

    // p in [0.23, 511.77] for all crop pixels -> i0 in [0,511], i1 <= 512: in-bounds.
    for (int a = 0; a < CHUNK; ++a) {
        float2 cs = s_tab[a];
        float p  = fmaf(X, cs.x, fmaf(Y, cs.y, 256.0f));
        float fi = floorf(p);
        float w  = p - fi;
        int   i0 = (int)fi;
        half2_t wp = __builtin_amdgcn_cvt_pkrtz(1.0f - w, w);  // (w0, w)
        uint4 A = cell[i0];
        uint4 B = cell[i0 + 1];
        cell += ND;
        // pair(batch b) = (A_b, B_b) as 2xf16; dot with (w0, w).
        acc0 = dot2(__builtin_amdgcn_perm(B.x, A.x, 0x05040100u), wp, acc0);
        acc1 = dot2(__builtin_amdgcn_perm(B.x, A.x, 0x07060302u), wp, acc1);
        acc2 = dot2(__builtin_amdgcn_perm(B.y, A.y, 0x05040100u), wp, acc2);
        acc3 = dot2(__builtin_amdgcn_perm(B.y, A.y, 0x07060302u), wp, acc3);
        acc4 = dot2(__builtin_amdgcn_perm(B.z, A.z, 0x05040100u), wp, acc4);
        acc5 = dot2(__builtin_amdgcn_perm(B.z, A.z, 0x07060302u), wp, acc5);
        acc6 = dot2(__builtin_amdgcn_perm(B.w, A.w, 0x05040100u), wp, acc6);
        acc7 = dot2(__builtin_amdgcn_perm(B.w, A.w, 0x07060302u), wp, acc7);
    }

    if (i < CROP && j < CROP) {
        float* p0 = g_part + (size_t)ch * 8 * NPIX + (size_t)i * CROP + j;
        p0[0 * NPIX] = acc0; p0[1 * NPIX] = acc1;
        p0[2 * NPIX] = acc2; p0[3 * NPIX] = acc3;
        p0[4 * NPIX] = acc4; p0[5 * NPIX] = acc5;
        p0[6 * NPIX] = acc6; p0[7 * NPIX] = acc7;
    }
}

// out[b][pix] = sum_ch part[ch][b][pix] * pi/NA
__global__ void combine_kernel(float* __restrict__ out) {
    int t = blockIdx.x * 256 + threadIdx.x;      // t over 8*NPIX, batch-major
    if (t >= 8 * NPIX) return;
    const float scale = (float)(3.14159265358979323846 / 1000.0);
    float s = 0.f;
    #pragma unroll
    for (int ch = 0; ch < NCH; ++ch) s += g_part[(size_t)ch * 8 * NPIX + t];
    out[t] = s * scale;
}

extern "C" void kernel_launch(void* const* d_in, const int* in_sizes, int n_in,
                              void* d_out, int out_size, void* d_ws, size_t ws_size,
                              hipStream_t stream) {
    const float* x = (const float*)d_in[0];
    float* out = (float*)d_out;

    table_kernel<<<(NA + 255) / 256, 256, 0, stream>>>();
    pack_kernel<<<(NA * ND + 255) / 256, 256, 0, stream>>>(x);

    dim3 bgrid(NTILE, NTILE, NCH);
    bp_kernel<<<bgrid, 256, 0, stream>>>();

    combine_kernel<<<(8 * NPIX + 255) / 256, 256, 0, stream>>>(out);
}

// Round 6
// 159.092 us; speedup vs baseline: 1.0791x; 1.0791x over previous
//
#include <hip/hip_runtime.h>

#define NA 1000
#define NCH 3
#define CHUNK 334              // max angles per chunk (334,334,332)
#define ND 513
#define ND2 512                // pair cells per angle: i0 in [0,511]
#define IMG 512
#define CROP 362
#define TOP ((IMG - CROP) / 2) // 75
#define NPIX (CROP * CROP)     // 131044
#define NTILE 23               // ceil(362/16)

typedef __fp16 half2_t __attribute__((ext_vector_type(2)));

// Static device buffers, fully rewritten every call (deterministic).
// g_pair: [angle][d(512)][32 B] = pre-assembled interp pairs:
//   words 0..7 = ( f16 x[b][a][d], f16 x[b][a][d+1] ) for b = 0..7.
// g_part: [chunk][batch][pix] f32 partial sums.
__device__ float2 g_tab[NA];
__device__ uint4  g_pair[(size_t)NA * ND2 * 2];
__device__ float  g_part[(size_t)NCH * 8 * NPIX];

__global__ void table_kernel() {
    int a = blockIdx.x * blockDim.x + threadIdx.x;
    if (a >= NA) return;
    double th = (double)a * (3.14159265358979323846 / (double)NA);
    float delta_f = (float)(2.0 * 0.13 / (double)(ND - 1));
    double inv = 1.0 / (double)delta_f;
    g_tab[a] = make_float2((float)(cos(th) * inv), (float)(sin(th) * inv));
}

// x[b][a][d] (b-major, f32) -> g_pair pre-permuted f16 pairs.
__global__ void pack_kernel(const float* __restrict__ x) {
    int t = blockIdx.x * blockDim.x + threadIdx.x;   // t = a*512 + d
    if (t >= NA * ND2) return;
    int a = t >> 9, d = t & 511;
    const float* p0 = x + (size_t)a * ND + d;
    const int S = NA * ND;
    unsigned int w[8];
    #pragma unroll
    for (int b = 0; b < 8; ++b) {
        half2_t h;
        h.x = (__fp16)p0[(size_t)b * S];
        h.y = (__fp16)p0[(size_t)b * S + 1];
        __builtin_memcpy(&w[b], &h, 4);
    }
    g_pair[2 * (size_t)t]     = make_uint4(w[0], w[1], w[2], w[3]);
    g_pair[2 * (size_t)t + 1] = make_uint4(w[4], w[5], w[6], w[7]);
}

__device__ __forceinline__ float dot2(unsigned int pair, half2_t wp, float acc) {
    half2_t h; __builtin_memcpy(&h, &pair, 4);
    float d;
    asm("v_dot2_f32_f16 %0, %1, %2, %3" : "=v"(d) : "v"(h), "v"(wp), "v"(acc));
    return d;
}

// block = 256 thr; each wave owns an 8x8 pixel patch (gather span ~11 cells).
// grid = (23, 23, 3 chunks) = 1587 blocks <= 7 blocks/CU capacity: all resident.
__launch_bounds__(256, 7)
__global__ void bp_kernel() {
    __shared__ float2 s_tab[CHUNK];
    int ch = blockIdx.z;
    int a0 = ch * CHUNK;
    int len = min(CHUNK, NA - a0);
    for (int t = threadIdx.x; t < len; t += 256) s_tab[t] = g_tab[a0 + t];
    __syncthreads();

    int wave = threadIdx.x >> 6;
    int lane = threadIdx.x & 63;
    int ti = (wave >> 1) * 8 + (lane >> 3);
    int tj = (wave & 1) * 8 + (lane & 7);
    int i = blockIdx.y * 16 + ti;      // -> X
    int j = blockIdx.x * 16 + tj;      // -> Y
    int ic = min(i, CROP - 1);
    int jc = min(j, CROP - 1);

    const float step = (float)(0.26 / 511.0);
    float X = fmaf((float)(TOP + ic), step, -0.13f);
    float Y = fmaf((float)(TOP + jc), step, -0.13f);

    // pair base for this chunk (uint4 units): (a0*512 + d)*2
    const uint4* __restrict__ pbase = g_pair + ((size_t)a0 << 10);

    // ---- software pipeline, depth 1 ----
    // prologue: angle 0
    float2 cs = s_tab[0];
    float p  = fmaf(X, cs.x, fmaf(Y, cs.y, 256.0f));
    float fi = floorf(p);
    half2_t wp = __builtin_amdgcn_cvt_pkrtz(fi - p + 1.0f, p - fi);  // (1-w, w)
    const uint4* ptr = pbase + ((size_t)(int)fi << 1);
    uint4 lo = ptr[0];
    uint4 hi = ptr[1];

    float acc0 = 0.f, acc1 = 0.f, acc2 = 0.f, acc3 = 0.f;
    float acc4 = 0.f, acc5 = 0.f, acc6 = 0.f, acc7 = 0.f;

    for (int a = 0; a < len; ++a) {
        // prefetch angle a+1 (last iter: reload current; harmless)
        int an = min(a + 1, len - 1);
        float2 cs2 = s_tab[an];
        float p2  = fmaf(X, cs2.x, fmaf(Y, cs2.y, 256.0f));
        float fi2 = floorf(p2);
        half2_t wp2 = __builtin_amdgcn_cvt_pkrtz(fi2 - p2 + 1.0f, p2 - fi2);
        const uint4* ptr2 = pbase + (((size_t)an << 9) + (size_t)(int)fi2 << 1);
        uint4 lo2 = ptr2[0];
        uint4 hi2 = ptr2[1];

        // consume current angle: 8 dot2, no perms
        acc0 = dot2(lo.x, wp, acc0);
        acc1 = dot2(lo.y, wp, acc1);
        acc2 = dot2(lo.z, wp, acc2);
        acc3 = dot2(lo.w, wp, acc3);
        acc4 = dot2(hi.x, wp, acc4);
        acc5 = dot2(hi.y, wp, acc5);
        acc6 = dot2(hi.z, wp, acc6);
        acc7 = dot2(hi.w, wp, acc7);

        lo = lo2; hi = hi2; wp = wp2;
    }

    if (i < CROP && j < CROP) {
        float* p0 = g_part + (size_t)ch * 8 * NPIX + (size_t)i * CROP + j;
        p0[0 * NPIX] = acc0; p0[1 * NPIX] = acc1;
        p0[2 * NPIX] = acc2; p0[3 * NPIX] = acc3;
        p0[4 * NPIX] = acc4; p0[5 * NPIX] = acc5;
        p0[6 * NPIX] = acc6; p0[7 * NPIX] = acc7;
    }
}

// out[b][pix] = sum_ch part[ch][b][pix] * pi/NA
__global__ void combine_kernel(float* __restrict__ out) {
    int t = blockIdx.x * 256 + threadIdx.x;      // t over 8*NPIX, batch-major
    if (t >= 8 * NPIX) return;
    const float scale = (float)(3.14159265358979323846 / 1000.0);
    float s = 0.f;
    #pragma unroll
    for (int ch = 0; ch < NCH; ++ch) s += g_part[(size_t)ch * 8 * NPIX + t];
    out[t] = s * scale;
}

extern "C" void kernel_launch(void* const* d_in, const int* in_sizes, int n_in,
                              void* d_out, int out_size, void* d_ws, size_t ws_size,
                              hipStream_t stream) {
    const float* x = (const float*)d_in[0];
    float* out = (float*)d_out;

    table_kernel<<<(NA + 255) / 256, 256, 0, stream>>>();
    pack_kernel<<<(NA * ND2 + 255) / 256, 256, 0, stream>>>(x);

    dim3 bgrid(NTILE, NTILE, NCH);
    bp_kernel<<<bgrid, 256, 0, stream>>>();

    combine_kernel<<<(8 * NPIX + 255) / 256, 256, 0, stream>>>(out);
}